// Round 13
// baseline (733.951 us; speedup 1.0000x reference)
//
#include <hip/hip_runtime.h>
#include <hip/hip_bf16.h>
#include <cmath>

#define NL 16
#define TSIZE (1u << 19)
#define TMASK (TSIZE - 1u)
#define NBINS (1u << 18)     // 18-bit Morton key (6 bits/axis, res 64)

typedef __attribute__((ext_vector_type(8))) short bf16x8;     // 8 bf16 (4 VGPRs)
typedef __attribute__((ext_vector_type(4))) float f32x4;

struct LevelParams {
  float scale[NL];
  unsigned res[NL];
  unsigned dense_mask;
};

static __device__ __forceinline__ short f2bf(float f) {
  __hip_bfloat16 h = __float2bfloat16(f);
  return *reinterpret_cast<short*>(&h);
}
static __device__ __forceinline__ short lo16(unsigned u) { return (short)(u & 0xffffu); }
static __device__ __forceinline__ short hi16(unsigned u) { return (short)(u >> 16); }

static __device__ __forceinline__ unsigned spread3(unsigned x) {
  x &= 0x3FFu;
  x = (x | (x << 16)) & 0x030000FFu;
  x = (x | (x << 8))  & 0x0300F00Fu;
  x = (x | (x << 4))  & 0x030C30C3u;
  x = (x | (x << 2))  & 0x09249249u;
  return x;
}
static __device__ __forceinline__ unsigned ray_key(float dx, float dy, float dz) {
  float X0 = dx * 0.49f + 0.49f;
  float X1 = dy * 0.49f + 0.49f;
  float X2 = dz * 0.49f + 0.49f;
  unsigned qx = (unsigned)(X0 * 64.0f); qx = qx > 63u ? 63u : qx;
  unsigned qy = (unsigned)(X1 * 64.0f); qy = qy > 63u ? 63u : qy;
  unsigned qz = (unsigned)(X2 * 64.0f); qz = qz > 63u ? 63u : qz;
  return spread3(qx) | (spread3(qy) << 1) | (spread3(qz) << 2);
}

// ============ Sort pipeline (r20-verified: 1 atomic pass, no sdirs) ========
__global__ __launch_bounds__(256)
void histidx_k(const float* __restrict__ dirs, unsigned* __restrict__ hist,
               unsigned* __restrict__ keyidx, int n) {
  int i = blockIdx.x * 256 + threadIdx.x;
  if (i >= n) return;
  unsigned key = ray_key(dirs[i * 3 + 0], dirs[i * 3 + 1], dirs[i * 3 + 2]);
  unsigned idx = atomicAdd(&hist[key], 1u);
  keyidx[i] = key | (idx << 18);
}

__global__ __launch_bounds__(256)
void scanA_k(unsigned* __restrict__ hist, unsigned* __restrict__ blockSums) {
  __shared__ unsigned sums[256];
  int bid = blockIdx.x, t = threadIdx.x;
  unsigned base = (unsigned)bid * 1024u + (unsigned)t * 4u;
  uint4 c = *(uint4*)&hist[base];
  unsigned s = c.x + c.y + c.z + c.w;
  sums[t] = s;
  __syncthreads();
  for (int off = 1; off < 256; off <<= 1) {
    unsigned v = (t >= off) ? sums[t - off] : 0u;
    __syncthreads();
    sums[t] += v;
    __syncthreads();
  }
  unsigned excl = sums[t] - s;
  uint4 o;
  o.x = excl;
  o.y = excl + c.x;
  o.z = excl + c.x + c.y;
  o.w = excl + c.x + c.y + c.z;
  *(uint4*)&hist[base] = o;
  if (t == 255) blockSums[bid] = sums[255];
}

__global__ __launch_bounds__(256)
void scanB_k(unsigned* __restrict__ blockSums) {
  __shared__ unsigned sums[256];
  int t = threadIdx.x;
  unsigned s = blockSums[t];
  sums[t] = s;
  __syncthreads();
  for (int off = 1; off < 256; off <<= 1) {
    unsigned v = (t >= off) ? sums[t - off] : 0u;
    __syncthreads();
    sums[t] += v;
    __syncthreads();
  }
  blockSums[t] = sums[t] - s;
}

__global__ __launch_bounds__(256)
void scatter2_k(const unsigned* __restrict__ keyidx,
                const unsigned* __restrict__ hist,
                const unsigned* __restrict__ bsums,
                unsigned* __restrict__ order, int n) {
  int i = blockIdx.x * 256 + threadIdx.x;
  if (i >= n) return;
  unsigned ki = keyidx[i];
  unsigned key = ki & (NBINS - 1u);
  unsigned idx = ki >> 18;
  unsigned pos = hist[key] + bsums[key >> 10] + idx;
  order[pos] = (unsigned)i;
}

// ============ FUSED encode + MLP ============
// r23: HALVE the serial gather chain without adding per-thread state (the
// measured 85-VGPR spill wall killed r1/r15/r16/r18's widening attempts):
// each ray's 16 levels split across 2 THREADS. thread t = (ray t>>1, half
// t&1); 4 rounds x 2 levels each (h=0: {j,j+4} of 0-7; h=1: {8+j,12+j}).
// Per-round register state identical to the r20 champion -> ~72 VGPR.
// Block covers 128 rays (grid 16384, %8==0), LDS unchanged 36864B
// (F = 16x130 words = 8.3KB aliased under the 18.4KB H1 region), MLP is one
// 32-ray batch per wave (same total MFMA), owner lane = 2*(t*16+nl) in-wave.
// r12 setprio (null, -2us noise) stripped.
#define ROWS 72
#define FSTR2 130   // F row stride in words (128 rays + 2 pad: banks spread)

__global__ __launch_bounds__(256, 3)
void fused_k(const float* __restrict__ dirs,
             const float* __restrict__ table,
             const unsigned* __restrict__ order,
             const float* __restrict__ W1, const float* __restrict__ b1,
             const float* __restrict__ W2, const float* __restrict__ b2,
             const float* __restrict__ W3, const float* __restrict__ b3,
             float* __restrict__ out, int n, LevelParams lp)
{
  // FH aliases: gather uses F[NL*FSTR2] unsigned (8320 B);
  // MLP uses H1T[4][32*ROWS] short (18432 B). Union = 18432 B.
  __shared__ unsigned FH[(4 * 32 * ROWS) / 2];   // 18.4 KB (union F / H1T)
  __shared__ short W1T[64 * ROWS];               // 9.2 KB
  __shared__ short W2T[64 * ROWS];               // 9.2 KB
  unsigned* F  = FH;
  short*    H1 = (short*)FH;

  int tid = threadIdx.x;

  // ---- stage weights (verified mlp_mfma4 staging; W1 rows permuted) ----
  {
    int nn = tid >> 2;
    int kg = tid & 3;
    bf16x8 v1a, v1b, v2a, v2b;
    #pragma unroll
    for (int j = 0; j < 8; ++j) {
      int k0 = kg * 16 + j, k1 = kg * 16 + 8 + j;
      v1a[j] = (k0 < 32) ? f2bf(W1[(k0 + 3) * 64 + nn])
             : (k0 < 35) ? f2bf(W1[(k0 - 32) * 64 + nn]) : (short)0;
      v1b[j] = (k1 < 32) ? f2bf(W1[(k1 + 3) * 64 + nn])
             : (k1 < 35) ? f2bf(W1[(k1 - 32) * 64 + nn]) : (short)0;
      v2a[j] = f2bf(W2[k0 * 64 + nn]);
      v2b[j] = f2bf(W2[k1 * 64 + nn]);
    }
    int wo = nn * ROWS + kg * 16;
    *(bf16x8*)&W1T[wo]     = v1a;
    *(bf16x8*)&W1T[wo + 8] = v1b;
    *(bf16x8*)&W2T[wo]     = v2a;
    *(bf16x8*)&W2T[wo + 8] = v2b;
  }

  // ---- XCD-aware swizzle: each XCD gets a contiguous range of sorted chunks ----
  int nwg = gridDim.x;
  int bidx = blockIdx.x;
  int chunk = ((nwg & 7) == 0) ? ((bidx & 7) * (nwg >> 3) + (bidx >> 3)) : bidx;

  // ---- gather: thread (rpos = tid>>1, h = tid&1) does 4 rounds x 2 levels ----
  int rpos = tid >> 1;                   // ray within block (0..127)
  int h = tid & 1;                       // level half: h*8 .. h*8+7
  int ray = chunk * 128 + rpos;
  int rcg = ray < n ? ray : (n - 1);
  unsigned o = order[rcg];               // original ray id (live for epilogue)
  float dxr = dirs[o * 3 + 0];
  float dyr = dirs[o * 3 + 1];
  float dzr = dirs[o * 3 + 2];

  float X0 = dxr * 0.49f + 0.49f;
  float X1 = dyr * 0.49f + 0.49f;
  float X2 = dzr * 0.49f + 0.49f;

  for (int j = 0; j < 4; ++j) {
    int lv[2];
    lv[0] = h * 8 + j;
    lv[1] = h * 8 + j + 4;

    float wa0[2][3], wa1[2][3];
    bool dns[2];
    unsigned didx[2][8];
    unsigned par[2][4];
    const float2* tb[2];

    #pragma unroll
    for (int g = 0; g < 2; ++g) {
      int level = lv[g];
      float s = lp.scale[level];
      unsigned r = lp.res[level];
      dns[g] = (lp.dense_mask >> level) & 1u;

      float px = X0 * s + 0.5f, py = X1 * s + 0.5f, pz = X2 * s + 0.5f;
      float gx = floorf(px), gy = floorf(py), gz = floorf(pz);
      float fx = px - gx, fy = py - gy, fz = pz - gz;
      unsigned ix = (unsigned)gx, iy = (unsigned)gy, iz = (unsigned)gz;

      wa1[g][0] = fx * fx * (3.0f - 2.0f * fx);
      wa1[g][1] = fy * fy * (3.0f - 2.0f * fy);
      wa1[g][2] = fz * fz * (3.0f - 2.0f * fz);
      wa0[g][0] = 1.0f - wa1[g][0];
      wa0[g][1] = 1.0f - wa1[g][1];
      wa0[g][2] = 1.0f - wa1[g][2];

      if (dns[g]) {
        unsigned r2 = r * r;
        unsigned x0 = ix, x1 = ix + 1u;
        unsigned y0 = iy * r, y1 = y0 + r;
        unsigned z0 = iz * r2, z1 = z0 + r2;
        didx[g][0] = x0 + y0 + z0; didx[g][1] = x1 + y0 + z0;
        didx[g][2] = x0 + y1 + z0; didx[g][3] = x1 + y1 + z0;
        didx[g][4] = x0 + y0 + z1; didx[g][5] = x1 + y0 + z1;
        didx[g][6] = x0 + y1 + z1; didx[g][7] = x1 + y1 + z1;
      } else {
        unsigned y0 = iy * 2654435761u, y1 = y0 + 2654435761u;  // uint32 wrap == ref
        unsigned z0 = iz * 805459861u,  z1 = z0 + 805459861u;
        unsigned p0 = (ix ^ y0 ^ z0) & TMASK;
        unsigned p1 = (ix ^ y1 ^ z0) & TMASK;
        unsigned p2 = (ix ^ y0 ^ z1) & TMASK;
        unsigned p3 = (ix ^ y1 ^ z1) & TMASK;
        didx[g][0] = p0 >> 1; didx[g][1] = p1 >> 1;
        didx[g][2] = p2 >> 1; didx[g][3] = p3 >> 1;
        par[g][0] = p0 & 1u; par[g][1] = p1 & 1u;
        par[g][2] = p2 & 1u; par[g][3] = p3 & 1u;
      }
      tb[g] = (const float2*)table + (size_t)level * TSIZE;
    }

    float2 v[2][8];
    float4 f4[2][4];
    #pragma unroll
    for (int g = 0; g < 2; ++g) {
      if (dns[g]) {
        #pragma unroll
        for (int c = 0; c < 8; ++c) v[g][c] = tb[g][didx[g][c]];
      } else {
        const float4* t4p = (const float4*)tb[g];
        #pragma unroll
        for (int c = 0; c < 4; ++c) f4[g][c] = t4p[didx[g][c]];
      }
    }
    #pragma unroll
    for (int g = 0; g < 2; ++g) {
      if (!dns[g]) {
        #pragma unroll
        for (int c = 0; c < 4; ++c) {
          float2 even, odd;
          even.x = f4[g][c].x; even.y = f4[g][c].y;
          odd.x  = f4[g][c].z; odd.y  = f4[g][c].w;
          bool od = par[g][c] != 0;
          v[g][2 * c]     = od ? odd : even;
          v[g][2 * c + 1] = od ? even : odd;
        }
      }
    }

    #pragma unroll
    for (int g = 0; g < 2; ++g) {
      float wx0 = wa0[g][0], wx1 = wa1[g][0];
      float wy0 = wa0[g][1], wy1 = wa1[g][1];
      float wz0 = wa0[g][2], wz1 = wa1[g][2];
      float wy0z0 = wy0 * wz0, wy1z0 = wy1 * wz0, wy0z1 = wy0 * wz1, wy1z1 = wy1 * wz1;
      float w000 = wx0 * wy0z0, w100 = wx1 * wy0z0;
      float w010 = wx0 * wy1z0, w110 = wx1 * wy1z0;
      float w001 = wx0 * wy0z1, w101 = wx1 * wy0z1;
      float w011 = wx0 * wy1z1, w111 = wx1 * wy1z1;

      float a0 = w000 * v[g][0].x + w100 * v[g][1].x + w010 * v[g][2].x + w110 * v[g][3].x
               + w001 * v[g][4].x + w101 * v[g][5].x + w011 * v[g][6].x + w111 * v[g][7].x;
      float a1 = w000 * v[g][0].y + w100 * v[g][1].y + w010 * v[g][2].y + w110 * v[g][3].y
               + w001 * v[g][4].y + w101 * v[g][5].y + w011 * v[g][6].y + w111 * v[g][7].y;

      unsigned packed = ((unsigned)f2bf(a0) & 0xffffu) | (((unsigned)f2bf(a1) & 0xffffu) << 16);
      F[lv[g] * FSTR2 + rpos] = packed;
    }
  }
  __syncthreads();   // F + weights visible to all lanes

  // ---- MLP phase: wave w handles local rays [32w, 32w+32), ONE batch ----
  int wave = tid >> 6, lane = tid & 63;
  int q = lane >> 4, nl = lane & 15;

  float b1v[4], b2v[4], w3v[4];
  #pragma unroll
  for (int t4 = 0; t4 < 4; ++t4) {
    b1v[t4] = b1[t4 * 16 + nl];
    b2v[t4] = b2[t4 * 16 + nl];
    w3v[t4] = W3[t4 * 16 + nl];
  }
  float b3s = b3[0];

  // Hoist ALL reads of F so F is dead before H1 aliases the storage.
  bf16x8 a0h[2];
  #pragma unroll
  for (int t = 0; t < 2; ++t) {
    int rl = wave * 32 + t * 16 + nl;      // local ray 0..127
    unsigned u0 = F[(q * 4 + 0) * FSTR2 + rl];
    unsigned u1 = F[(q * 4 + 1) * FSTR2 + rl];
    unsigned u2 = F[(q * 4 + 2) * FSTR2 + rl];
    unsigned u3 = F[(q * 4 + 3) * FSTR2 + rl];
    a0h[t][0] = lo16(u0); a0h[t][1] = hi16(u0);
    a0h[t][2] = lo16(u1); a0h[t][3] = hi16(u1);
    a0h[t][4] = lo16(u2); a0h[t][5] = hi16(u2);
    a0h[t][6] = lo16(u3); a0h[t][7] = hi16(u3);
  }
  __syncthreads();   // all F reads drained before H1 aliases the storage

  {
    bf16x8 a1[2];
    #pragma unroll
    for (int t = 0; t < 2; ++t) {
      a1[t][0] = 0; a1[t][1] = 0; a1[t][2] = 0; a1[t][3] = 0;
      a1[t][4] = 0; a1[t][5] = 0; a1[t][6] = 0; a1[t][7] = 0;
      // dirs for k'=32..34: owner thread of local ray rl is tid = 2*rl
      // -> within this wave, shfl lane = 2*(t*16+nl)
      int sl = 2 * (t * 16 + nl);
      float sdx = __shfl(dxr, sl, 64);
      float sdy = __shfl(dyr, sl, 64);
      float sdz = __shfl(dzr, sl, 64);
      if (q == 0) {
        a1[t][0] = f2bf(sdx);
        a1[t][1] = f2bf(sdy);
        a1[t][2] = f2bf(sdz);
      }
    }

    f32x4 acc[2][4];
    #pragma unroll
    for (int t4 = 0; t4 < 4; ++t4) {
      int brow = (t4 * 16 + nl) * ROWS;
      bf16x8 bt0 = *(const bf16x8*)&W1T[brow + q * 8];
      bf16x8 bt1 = *(const bf16x8*)&W1T[brow + 32 + q * 8];
      #pragma unroll
      for (int t = 0; t < 2; ++t) {
        f32x4 z = {0.f, 0.f, 0.f, 0.f};
        z = __builtin_amdgcn_mfma_f32_16x16x32_bf16(a0h[t], bt0, z, 0, 0, 0);
        z = __builtin_amdgcn_mfma_f32_16x16x32_bf16(a1[t], bt1, z, 0, 0, 0);
        acc[t][t4] = z;
      }
    }
    #pragma unroll
    for (int t = 0; t < 2; ++t)
      #pragma unroll
      for (int t4 = 0; t4 < 4; ++t4)
        #pragma unroll
        for (int i = 0; i < 4; ++i) {
          float v = fmaxf(acc[t][t4][i] + b1v[t4], 0.0f);
          H1[wave * (32 * ROWS) + (t * 16 + q * 4 + i) * ROWS + t4 * 16 + nl] = f2bf(v);
        }
    __syncthreads();   // H1 visible + compiler fence

    #pragma unroll
    for (int t4 = 0; t4 < 4; ++t4) {
      int brow = (t4 * 16 + nl) * ROWS;
      bf16x8 bt0 = *(const bf16x8*)&W2T[brow + q * 8];
      bf16x8 bt1 = *(const bf16x8*)&W2T[brow + 32 + q * 8];
      #pragma unroll
      for (int t = 0; t < 2; ++t) {
        bf16x8 h0  = *(const bf16x8*)&H1[wave * (32 * ROWS) + (t * 16 + nl) * ROWS + q * 8];
        bf16x8 h1f = *(const bf16x8*)&H1[wave * (32 * ROWS) + (t * 16 + nl) * ROWS + 32 + q * 8];
        f32x4 z = {0.f, 0.f, 0.f, 0.f};
        z = __builtin_amdgcn_mfma_f32_16x16x32_bf16(h0, bt0, z, 0, 0, 0);
        z = __builtin_amdgcn_mfma_f32_16x16x32_bf16(h1f, bt1, z, 0, 0, 0);
        acc[t][t4] = z;
      }
    }

    #pragma unroll
    for (int t = 0; t < 2; ++t) {
      float part[4] = {0.f, 0.f, 0.f, 0.f};
      #pragma unroll
      for (int t4 = 0; t4 < 4; ++t4)
        #pragma unroll
        for (int i = 0; i < 4; ++i) {
          float v = fmaxf(acc[t][t4][i] + b2v[t4], 0.0f);
          part[i] = fmaf(v, w3v[t4], part[i]);
        }
      #pragma unroll
      for (int s = 1; s < 16; s <<= 1) {
        #pragma unroll
        for (int i = 0; i < 4; ++i) part[i] += __shfl_xor(part[i], s, 64);
      }
      // original ray ids for this output quad from owner lanes (same wave)
      unsigned oi[4];
      #pragma unroll
      for (int i = 0; i < 4; ++i)
        oi[i] = __shfl(o, 2 * (t * 16 + q * 4 + i), 64);
      if (nl == 0) {
        int orow = chunk * 128 + wave * 32 + t * 16 + q * 4;
        #pragma unroll
        for (int i = 0; i < 4; ++i) {
          if (orow + i < n) {
            float v = part[i] + b3s + 1.0f;
            out[oi[i]] = fmaxf(v, 0.0f) + log1pf(expf(-fabsf(v)));
          }
        }
      }
    }
  }
}

extern "C" void kernel_launch(void* const* d_in, const int* in_sizes, int n_in,
                              void* d_out, int out_size, void* d_ws, size_t ws_size,
                              hipStream_t stream) {
  const float* dirs  = (const float*)d_in[0];
  const float* table = (const float*)d_in[1];
  const float* W1 = (const float*)d_in[2];
  const float* b1 = (const float*)d_in[3];
  const float* W2 = (const float*)d_in[4];
  const float* b2 = (const float*)d_in[5];
  const float* W3 = (const float*)d_in[6];
  const float* b3 = (const float*)d_in[7];
  float* out = (float*)d_out;
  int n = in_sizes[0] / 3;

  LevelParams lp;
  double pls = std::exp(std::log(2048.0 / 16.0) / 15.0);
  unsigned dm = 0;
  for (int l = 0; l < NL; ++l) {
    double scale = 16.0 * std::pow(pls, (double)l) - 1.0;
    lp.scale[l] = (float)scale;
    long long res = (long long)std::ceil(scale) + 1;
    lp.res[l] = (unsigned)res;
    if (res * res * res <= (long long)TSIZE) dm |= (1u << l);
  }
  lp.dense_mask = dm;

  size_t order_bytes  = (size_t)n * 4;
  size_t keyidx_bytes = (size_t)n * 4;
  size_t hist_bytes   = (size_t)NBINS * 4;

  int blocks256 = (n + 255) / 256;
  int blocks128 = (n + 127) / 128;

  char* base = (char*)d_ws;
  unsigned* order  = (unsigned*)base;
  unsigned* keyidx = (unsigned*)(base + order_bytes);
  unsigned* hist   = (unsigned*)(base + order_bytes + keyidx_bytes);
  unsigned* bsums  = (unsigned*)(base + order_bytes + keyidx_bytes + hist_bytes);

  hipMemsetAsync(hist, 0, hist_bytes, stream);
  hipLaunchKernelGGL(histidx_k, dim3(blocks256), dim3(256), 0, stream,
                     dirs, hist, keyidx, n);
  hipLaunchKernelGGL(scanA_k, dim3(256), dim3(256), 0, stream, hist, bsums);
  hipLaunchKernelGGL(scanB_k, dim3(1), dim3(256), 0, stream, bsums);
  hipLaunchKernelGGL(scatter2_k, dim3(blocks256), dim3(256), 0, stream,
                     keyidx, hist, bsums, order, n);
  hipLaunchKernelGGL(fused_k, dim3(blocks128), dim3(256), 0, stream,
                     dirs, table, order, W1, b1, W2, b2, W3, b3, out, n, lp);
}

// Round 14
// 611.071 us; speedup vs baseline: 1.2011x; 1.2011x over previous
//
#include <hip/hip_runtime.h>
#include <hip/hip_bf16.h>
#include <cmath>

#define NL 16
#define TSIZE (1u << 19)
#define TMASK (TSIZE - 1u)
#define NBINS (1u << 18)     // 18-bit Morton key (6 bits/axis, res 64)

typedef __attribute__((ext_vector_type(8))) short bf16x8;     // 8 bf16 (4 VGPRs)
typedef __attribute__((ext_vector_type(4))) float f32x4;

struct LevelParams {
  float scale[NL];
  unsigned res[NL];
  unsigned dense_mask;
};

static __device__ __forceinline__ short f2bf(float f) {
  __hip_bfloat16 h = __float2bfloat16(f);
  return *reinterpret_cast<short*>(&h);
}
static __device__ __forceinline__ short lo16(unsigned u) { return (short)(u & 0xffffu); }
static __device__ __forceinline__ short hi16(unsigned u) { return (short)(u >> 16); }

static __device__ __forceinline__ unsigned spread3(unsigned x) {
  x &= 0x3FFu;
  x = (x | (x << 16)) & 0x030000FFu;
  x = (x | (x << 8))  & 0x0300F00Fu;
  x = (x | (x << 4))  & 0x030C30C3u;
  x = (x | (x << 2))  & 0x09249249u;
  return x;
}
static __device__ __forceinline__ unsigned ray_key(float dx, float dy, float dz) {
  float X0 = dx * 0.49f + 0.49f;
  float X1 = dy * 0.49f + 0.49f;
  float X2 = dz * 0.49f + 0.49f;
  unsigned qx = (unsigned)(X0 * 64.0f); qx = qx > 63u ? 63u : qx;
  unsigned qy = (unsigned)(X1 * 64.0f); qy = qy > 63u ? 63u : qy;
  unsigned qz = (unsigned)(X2 * 64.0f); qz = qz > 63u ? 63u : qz;
  return spread3(qx) | (spread3(qy) << 1) | (spread3(qz) << 2);
}

// ============ Sort pipeline (r20-verified: 1 atomic pass, no sdirs) ========
// Measured floor: ~243us (memset+histidx+scanA+scanB+scatter2). The single
// atomic pass (~70us) is mandatory; scans are tiny; coop-fused version
// REGRESSED (r21: grid.sync ~100us each on 8 non-coherent XCD L2s).
__global__ __launch_bounds__(256)
void histidx_k(const float* __restrict__ dirs, unsigned* __restrict__ hist,
               unsigned* __restrict__ keyidx, int n) {
  int i = blockIdx.x * 256 + threadIdx.x;
  if (i >= n) return;
  unsigned key = ray_key(dirs[i * 3 + 0], dirs[i * 3 + 1], dirs[i * 3 + 2]);
  unsigned idx = atomicAdd(&hist[key], 1u);
  keyidx[i] = key | (idx << 18);
}

__global__ __launch_bounds__(256)
void scanA_k(unsigned* __restrict__ hist, unsigned* __restrict__ blockSums) {
  __shared__ unsigned sums[256];
  int bid = blockIdx.x, t = threadIdx.x;
  unsigned base = (unsigned)bid * 1024u + (unsigned)t * 4u;
  uint4 c = *(uint4*)&hist[base];
  unsigned s = c.x + c.y + c.z + c.w;
  sums[t] = s;
  __syncthreads();
  for (int off = 1; off < 256; off <<= 1) {
    unsigned v = (t >= off) ? sums[t - off] : 0u;
    __syncthreads();
    sums[t] += v;
    __syncthreads();
  }
  unsigned excl = sums[t] - s;
  uint4 o;
  o.x = excl;
  o.y = excl + c.x;
  o.z = excl + c.x + c.y;
  o.w = excl + c.x + c.y + c.z;
  *(uint4*)&hist[base] = o;
  if (t == 255) blockSums[bid] = sums[255];
}

__global__ __launch_bounds__(256)
void scanB_k(unsigned* __restrict__ blockSums) {
  __shared__ unsigned sums[256];
  int t = threadIdx.x;
  unsigned s = blockSums[t];
  sums[t] = s;
  __syncthreads();
  for (int off = 1; off < 256; off <<= 1) {
    unsigned v = (t >= off) ? sums[t - off] : 0u;
    __syncthreads();
    sums[t] += v;
    __syncthreads();
  }
  blockSums[t] = sums[t] - s;
}

// scatter with NO atomics and NO sdirs: pos = hist[key] + bsums[key>>10] + idx
__global__ __launch_bounds__(256)
void scatter2_k(const unsigned* __restrict__ keyidx,
                const unsigned* __restrict__ hist,
                const unsigned* __restrict__ bsums,
                unsigned* __restrict__ order, int n) {
  int i = blockIdx.x * 256 + threadIdx.x;
  if (i >= n) return;
  unsigned ki = keyidx[i];
  unsigned key = ki & (NBINS - 1u);
  unsigned idx = ki >> 18;
  unsigned pos = hist[key] + bsums[key >> 10] + idx;
  order[pos] = (unsigned)i;
}

// ============ FUSED encode + MLP (r20 champion, restored verbatim) =========
// 370us measured. Closed levers (all benched): per-thread gather widening
// spills at >85 VGPR (r1/r16/r18); 2-thread/ray split loses MLP/staging
// amortization + halves per-CU ray concurrency (r23, 490us); 5-block LDS
// shave doesn't materialize a 5th block + wave-fences regress (r15);
// setprio null (r22); coop grid.sync 100us/barrier (r21).
#define ROWS 72
#define FSTR 257   // F row stride in words (breaks 256-periodicity -> banks spread)

__global__ __launch_bounds__(256, 3)
void fused_k(const float* __restrict__ dirs,
             const float* __restrict__ table,
             const unsigned* __restrict__ order,
             const float* __restrict__ W1, const float* __restrict__ b1,
             const float* __restrict__ W2, const float* __restrict__ b2,
             const float* __restrict__ W3, const float* __restrict__ b3,
             float* __restrict__ out, int n, LevelParams lp)
{
  // FH aliases: gather phase uses it as F[NL*FSTR] unsigned (16448 B);
  // MLP batch loop uses it as H1T[4][32*ROWS] short (18432 B).
  __shared__ unsigned FH[(4 * 32 * ROWS) / 2];   // 18.4 KB (union F / H1T)
  __shared__ short W1T[64 * ROWS];               // 9.2 KB
  __shared__ short W2T[64 * ROWS];               // 9.2 KB
  unsigned* F  = FH;
  short*    H1 = (short*)FH;

  int tid = threadIdx.x;

  // ---- stage weights (verified mlp_mfma4 staging; W1 rows permuted) ----
  {
    int nn = tid >> 2;
    int kg = tid & 3;
    bf16x8 v1a, v1b, v2a, v2b;
    #pragma unroll
    for (int j = 0; j < 8; ++j) {
      int k0 = kg * 16 + j, k1 = kg * 16 + 8 + j;
      v1a[j] = (k0 < 32) ? f2bf(W1[(k0 + 3) * 64 + nn])
             : (k0 < 35) ? f2bf(W1[(k0 - 32) * 64 + nn]) : (short)0;
      v1b[j] = (k1 < 32) ? f2bf(W1[(k1 + 3) * 64 + nn])
             : (k1 < 35) ? f2bf(W1[(k1 - 32) * 64 + nn]) : (short)0;
      v2a[j] = f2bf(W2[k0 * 64 + nn]);
      v2b[j] = f2bf(W2[k1 * 64 + nn]);
    }
    int wo = nn * ROWS + kg * 16;
    *(bf16x8*)&W1T[wo]     = v1a;
    *(bf16x8*)&W1T[wo + 8] = v1b;
    *(bf16x8*)&W2T[wo]     = v2a;
    *(bf16x8*)&W2T[wo + 8] = v2b;
  }

  // ---- XCD-aware swizzle: each XCD gets a contiguous range of sorted chunks ----
  int nwg = gridDim.x;
  int bidx = blockIdx.x;
  int chunk = ((nwg & 7) == 0) ? ((bidx & 7) * (nwg >> 3) + (bidx >> 3)) : bidx;

  // ---- gather phase: thread owns sorted pos chunk*256+tid ----
  int ray = chunk * 256 + tid;
  int rcg = ray < n ? ray : (n - 1);
  unsigned o = order[rcg];               // original ray id (live for epilogue)
  float dxr = dirs[o * 3 + 0];
  float dyr = dirs[o * 3 + 1];
  float dzr = dirs[o * 3 + 2];

  float X0 = dxr * 0.49f + 0.49f;
  float X1 = dyr * 0.49f + 0.49f;
  float X2 = dzr * 0.49f + 0.49f;

  for (int l0 = 0; l0 < 8; ++l0) {
    float wa0[2][3], wa1[2][3];
    bool dns[2];
    unsigned didx[2][8];
    unsigned par[2][4];
    const float2* tb[2];

    #pragma unroll
    for (int g = 0; g < 2; ++g) {
      int level = l0 + g * 8;
      float s = lp.scale[level];
      unsigned r = lp.res[level];
      dns[g] = (lp.dense_mask >> level) & 1u;

      float px = X0 * s + 0.5f, py = X1 * s + 0.5f, pz = X2 * s + 0.5f;
      float gx = floorf(px), gy = floorf(py), gz = floorf(pz);
      float fx = px - gx, fy = py - gy, fz = pz - gz;
      unsigned ix = (unsigned)gx, iy = (unsigned)gy, iz = (unsigned)gz;

      wa1[g][0] = fx * fx * (3.0f - 2.0f * fx);
      wa1[g][1] = fy * fy * (3.0f - 2.0f * fy);
      wa1[g][2] = fz * fz * (3.0f - 2.0f * fz);
      wa0[g][0] = 1.0f - wa1[g][0];
      wa0[g][1] = 1.0f - wa1[g][1];
      wa0[g][2] = 1.0f - wa1[g][2];

      if (dns[g]) {
        unsigned r2 = r * r;
        unsigned x0 = ix, x1 = ix + 1u;
        unsigned y0 = iy * r, y1 = y0 + r;
        unsigned z0 = iz * r2, z1 = z0 + r2;
        didx[g][0] = x0 + y0 + z0; didx[g][1] = x1 + y0 + z0;
        didx[g][2] = x0 + y1 + z0; didx[g][3] = x1 + y1 + z0;
        didx[g][4] = x0 + y0 + z1; didx[g][5] = x1 + y0 + z1;
        didx[g][6] = x0 + y1 + z1; didx[g][7] = x1 + y1 + z1;
      } else {
        unsigned y0 = iy * 2654435761u, y1 = y0 + 2654435761u;  // uint32 wrap == ref
        unsigned z0 = iz * 805459861u,  z1 = z0 + 805459861u;
        unsigned p0 = (ix ^ y0 ^ z0) & TMASK;
        unsigned p1 = (ix ^ y1 ^ z0) & TMASK;
        unsigned p2 = (ix ^ y0 ^ z1) & TMASK;
        unsigned p3 = (ix ^ y1 ^ z1) & TMASK;
        didx[g][0] = p0 >> 1; didx[g][1] = p1 >> 1;
        didx[g][2] = p2 >> 1; didx[g][3] = p3 >> 1;
        par[g][0] = p0 & 1u; par[g][1] = p1 & 1u;
        par[g][2] = p2 & 1u; par[g][3] = p3 & 1u;
      }
      tb[g] = (const float2*)table + (size_t)level * TSIZE;
    }

    float2 v[2][8];
    float4 f4[2][4];
    #pragma unroll
    for (int g = 0; g < 2; ++g) {
      if (dns[g]) {
        #pragma unroll
        for (int c = 0; c < 8; ++c) v[g][c] = tb[g][didx[g][c]];
      } else {
        const float4* t4p = (const float4*)tb[g];
        #pragma unroll
        for (int c = 0; c < 4; ++c) f4[g][c] = t4p[didx[g][c]];
      }
    }
    #pragma unroll
    for (int g = 0; g < 2; ++g) {
      if (!dns[g]) {
        #pragma unroll
        for (int c = 0; c < 4; ++c) {
          float2 even, odd;
          even.x = f4[g][c].x; even.y = f4[g][c].y;
          odd.x  = f4[g][c].z; odd.y  = f4[g][c].w;
          bool od = par[g][c] != 0;
          v[g][2 * c]     = od ? odd : even;
          v[g][2 * c + 1] = od ? even : odd;
        }
      }
    }

    #pragma unroll
    for (int g = 0; g < 2; ++g) {
      float wx0 = wa0[g][0], wx1 = wa1[g][0];
      float wy0 = wa0[g][1], wy1 = wa1[g][1];
      float wz0 = wa0[g][2], wz1 = wa1[g][2];
      float wy0z0 = wy0 * wz0, wy1z0 = wy1 * wz0, wy0z1 = wy0 * wz1, wy1z1 = wy1 * wz1;
      float w000 = wx0 * wy0z0, w100 = wx1 * wy0z0;
      float w010 = wx0 * wy1z0, w110 = wx1 * wy1z0;
      float w001 = wx0 * wy0z1, w101 = wx1 * wy0z1;
      float w011 = wx0 * wy1z1, w111 = wx1 * wy1z1;

      float a0 = w000 * v[g][0].x + w100 * v[g][1].x + w010 * v[g][2].x + w110 * v[g][3].x
               + w001 * v[g][4].x + w101 * v[g][5].x + w011 * v[g][6].x + w111 * v[g][7].x;
      float a1 = w000 * v[g][0].y + w100 * v[g][1].y + w010 * v[g][2].y + w110 * v[g][3].y
               + w001 * v[g][4].y + w101 * v[g][5].y + w011 * v[g][6].y + w111 * v[g][7].y;

      int level = l0 + g * 8;
      unsigned packed = ((unsigned)f2bf(a0) & 0xffffu) | (((unsigned)f2bf(a1) & 0xffffu) << 16);
      F[level * FSTR + tid] = packed;
    }
  }
  __syncthreads();   // F + weights visible to all lanes

  // ---- MLP phase ----
  int wave = tid >> 6, lane = tid & 63;
  int q = lane >> 4, nl = lane & 15;

  float b1v[4], b2v[4], w3v[4];
  #pragma unroll
  for (int t4 = 0; t4 < 4; ++t4) {
    b1v[t4] = b1[t4 * 16 + nl];
    b2v[t4] = b2[t4 * 16 + nl];
    w3v[t4] = W3[t4 * 16 + nl];
  }
  float b3s = b3[0];

  // Hoist ALL reads of F (A-fragments for both batches) so F is dead before
  // the batch loop writes H1 into the same storage.
  bf16x8 a0h[2][2];
  #pragma unroll
  for (int batch = 0; batch < 2; ++batch) {
    #pragma unroll
    for (int t = 0; t < 2; ++t) {
      int rl = wave * 64 + batch * 32 + t * 16 + nl;   // local ray 0..255
      unsigned u0 = F[(q * 4 + 0) * FSTR + rl];
      unsigned u1 = F[(q * 4 + 1) * FSTR + rl];
      unsigned u2 = F[(q * 4 + 2) * FSTR + rl];
      unsigned u3 = F[(q * 4 + 3) * FSTR + rl];
      a0h[batch][t][0] = lo16(u0); a0h[batch][t][1] = hi16(u0);
      a0h[batch][t][2] = lo16(u1); a0h[batch][t][3] = hi16(u1);
      a0h[batch][t][4] = lo16(u2); a0h[batch][t][5] = hi16(u2);
      a0h[batch][t][6] = lo16(u3); a0h[batch][t][7] = hi16(u3);
    }
  }
  __syncthreads();   // all F reads drained before H1 aliases the storage

  #pragma unroll
  for (int batch = 0; batch < 2; ++batch) {   // wave: 2 batches x 32 rays
    int lbase = wave * 64 + batch * 32;       // local ray base within block

    bf16x8 a1[2];
    #pragma unroll
    for (int t = 0; t < 2; ++t) {
      a1[t][0] = 0; a1[t][1] = 0; a1[t][2] = 0; a1[t][3] = 0;
      a1[t][4] = 0; a1[t][5] = 0; a1[t][6] = 0; a1[t][7] = 0;
      // dirs for k'=32..34: owner lane (batch*32+t*16+nl) is in this wave
      int sl = batch * 32 + t * 16 + nl;
      float sdx = __shfl(dxr, sl, 64);
      float sdy = __shfl(dyr, sl, 64);
      float sdz = __shfl(dzr, sl, 64);
      if (q == 0) {
        a1[t][0] = f2bf(sdx);
        a1[t][1] = f2bf(sdy);
        a1[t][2] = f2bf(sdz);
      }
    }

    f32x4 acc[2][4];
    #pragma unroll
    for (int t4 = 0; t4 < 4; ++t4) {
      int brow = (t4 * 16 + nl) * ROWS;
      bf16x8 bt0 = *(const bf16x8*)&W1T[brow + q * 8];
      bf16x8 bt1 = *(const bf16x8*)&W1T[brow + 32 + q * 8];
      #pragma unroll
      for (int t = 0; t < 2; ++t) {
        f32x4 z = {0.f, 0.f, 0.f, 0.f};
        z = __builtin_amdgcn_mfma_f32_16x16x32_bf16(a0h[batch][t], bt0, z, 0, 0, 0);
        z = __builtin_amdgcn_mfma_f32_16x16x32_bf16(a1[t], bt1, z, 0, 0, 0);
        acc[t][t4] = z;
      }
    }
    #pragma unroll
    for (int t = 0; t < 2; ++t)
      #pragma unroll
      for (int t4 = 0; t4 < 4; ++t4)
        #pragma unroll
        for (int i = 0; i < 4; ++i) {
          float v = fmaxf(acc[t][t4][i] + b1v[t4], 0.0f);
          H1[wave * (32 * ROWS) + (t * 16 + q * 4 + i) * ROWS + t4 * 16 + nl] = f2bf(v);
        }
    __syncthreads();   // H1 visible + compiler fence

    #pragma unroll
    for (int t4 = 0; t4 < 4; ++t4) {
      int brow = (t4 * 16 + nl) * ROWS;
      bf16x8 bt0 = *(const bf16x8*)&W2T[brow + q * 8];
      bf16x8 bt1 = *(const bf16x8*)&W2T[brow + 32 + q * 8];
      #pragma unroll
      for (int t = 0; t < 2; ++t) {
        bf16x8 h0  = *(const bf16x8*)&H1[wave * (32 * ROWS) + (t * 16 + nl) * ROWS + q * 8];
        bf16x8 h1f = *(const bf16x8*)&H1[wave * (32 * ROWS) + (t * 16 + nl) * ROWS + 32 + q * 8];
        f32x4 z = {0.f, 0.f, 0.f, 0.f};
        z = __builtin_amdgcn_mfma_f32_16x16x32_bf16(h0, bt0, z, 0, 0, 0);
        z = __builtin_amdgcn_mfma_f32_16x16x32_bf16(h1f, bt1, z, 0, 0, 0);
        acc[t][t4] = z;
      }
    }

    #pragma unroll
    for (int t = 0; t < 2; ++t) {
      float part[4] = {0.f, 0.f, 0.f, 0.f};
      #pragma unroll
      for (int t4 = 0; t4 < 4; ++t4)
        #pragma unroll
        for (int i = 0; i < 4; ++i) {
          float v = fmaxf(acc[t][t4][i] + b2v[t4], 0.0f);
          part[i] = fmaf(v, w3v[t4], part[i]);
        }
      #pragma unroll
      for (int s = 1; s < 16; s <<= 1) {
        #pragma unroll
        for (int i = 0; i < 4; ++i) part[i] += __shfl_xor(part[i], s, 64);
      }
      // original ray ids for this output quad from owner lanes (same wave)
      unsigned oi[4];
      #pragma unroll
      for (int i = 0; i < 4; ++i)
        oi[i] = __shfl(o, batch * 32 + t * 16 + q * 4 + i, 64);
      if (nl == 0) {
        int orow = chunk * 256 + lbase + t * 16 + q * 4;
        #pragma unroll
        for (int i = 0; i < 4; ++i) {
          if (orow + i < n) {
            float v = part[i] + b3s + 1.0f;
            out[oi[i]] = fmaxf(v, 0.0f) + log1pf(expf(-fabsf(v)));
          }
        }
      }
    }
    __syncthreads();   // WAR: next batch's H1 write must not pass reads
  }
}

extern "C" void kernel_launch(void* const* d_in, const int* in_sizes, int n_in,
                              void* d_out, int out_size, void* d_ws, size_t ws_size,
                              hipStream_t stream) {
  const float* dirs  = (const float*)d_in[0];
  const float* table = (const float*)d_in[1];
  const float* W1 = (const float*)d_in[2];
  const float* b1 = (const float*)d_in[3];
  const float* W2 = (const float*)d_in[4];
  const float* b2 = (const float*)d_in[5];
  const float* W3 = (const float*)d_in[6];
  const float* b3 = (const float*)d_in[7];
  float* out = (float*)d_out;
  int n = in_sizes[0] / 3;

  LevelParams lp;
  double pls = std::exp(std::log(2048.0 / 16.0) / 15.0);
  unsigned dm = 0;
  for (int l = 0; l < NL; ++l) {
    double scale = 16.0 * std::pow(pls, (double)l) - 1.0;
    lp.scale[l] = (float)scale;
    long long res = (long long)std::ceil(scale) + 1;
    lp.res[l] = (unsigned)res;
    if (res * res * res <= (long long)TSIZE) dm |= (1u << l);
  }
  lp.dense_mask = dm;

  size_t order_bytes  = (size_t)n * 4;
  size_t keyidx_bytes = (size_t)n * 4;
  size_t hist_bytes   = (size_t)NBINS * 4;

  int blocks256 = (n + 255) / 256;

  char* base = (char*)d_ws;
  unsigned* order  = (unsigned*)base;
  unsigned* keyidx = (unsigned*)(base + order_bytes);
  unsigned* hist   = (unsigned*)(base + order_bytes + keyidx_bytes);
  unsigned* bsums  = (unsigned*)(base + order_bytes + keyidx_bytes + hist_bytes);

  hipMemsetAsync(hist, 0, hist_bytes, stream);
  hipLaunchKernelGGL(histidx_k, dim3(blocks256), dim3(256), 0, stream,
                     dirs, hist, keyidx, n);
  hipLaunchKernelGGL(scanA_k, dim3(256), dim3(256), 0, stream, hist, bsums);
  hipLaunchKernelGGL(scanB_k, dim3(1), dim3(256), 0, stream, bsums);
  hipLaunchKernelGGL(scatter2_k, dim3(blocks256), dim3(256), 0, stream,
                     keyidx, hist, bsums, order, n);
  hipLaunchKernelGGL(fused_k, dim3(blocks256), dim3(256), 0, stream,
                     dirs, table, order, W1, b1, W2, b2, W3, b3, out, n, lp);
}